// Round 5
// baseline (324.084 us; speedup 1.0000x reference)
//
#include <hip/hip_runtime.h>
#include <hip/hip_fp16.h>
#include <hip/hip_cooperative_groups.h>
#include <math.h>

namespace cg = cooperative_groups;

#define N_NODES 50000
#define N_EDGES 1600000
#define BSHIFT 6            // bucket = dst>>6 (64 nodes per bucket)
#define NB_BUCKETS 782      // ceil(50000/64)
#define NBLK 256            // cooperative grid: 1 block per CU
#define NTHR 1024           // 16 waves per block
#define PART_CHUNK 6250     // 1600000 / 256 exactly -> 1 chunk per block
#define EPT 7               // ceil(6250/1024) edges per thread
#define CAP 3072            // per-bucket slot stride; mean 2048, sigma ~45
#define ZSTRIDE 32          // z row = 32 halves = 64B, one cache line
#define GREP 16             // G replicas: avoids deep per-line atomic chains
#define DEG_BLOCKS 64       // blocks [0,64) do degree pass; [64,256) do feat

// ---------- DPP helpers (VALU-pipe cross-lane, no LDS) ----------
template<int CTRL>
__device__ inline float dpp_mov(float x){
    return __int_as_float(__builtin_amdgcn_update_dpp(0, __float_as_int(x), CTRL, 0xf, 0xf, false));
}
__device__ inline float wave_sum_dpp(float x){
    x += dpp_mov<0x111>(x);   // row_shr:1
    x += dpp_mov<0x112>(x);   // row_shr:2
    x += dpp_mov<0x114>(x);   // row_shr:4
    x += dpp_mov<0x118>(x);   // row_shr:8
    x += dpp_mov<0x142>(x);   // row_bcast:15
    x += dpp_mov<0x143>(x);   // row_bcast:31
    return x;
}
__device__ inline float lane63(float x){
    return __int_as_float(__builtin_amdgcn_readlane(__float_as_int(x), 63));
}
#define DPP_XOR1 0xB1   // quad_perm [1,0,3,2]
#define DPP_XOR2 0x4E   // quad_perm [2,3,0,1]

// ---------- complex 2x2 helpers ----------
struct C2 { float x, y; };
__device__ inline C2 mkc(float x, float y){ C2 r; r.x=x; r.y=y; return r; }
__device__ inline C2 cmul(C2 a, C2 b){ return mkc(a.x*b.x - a.y*b.y, a.x*b.y + a.y*b.x); }
__device__ inline C2 cadd(C2 a, C2 b){ return mkc(a.x+b.x, a.y+b.y); }

__device__ inline int get_edge(const void* ei, int is64, long long idx){
    if (is64) return (int)((const long long*)ei)[idx];
    return ((const int*)ei)[idx];
}

// ---------- gather accumulate: acc += w * zrow (fp16x2 unpack, fp32 fma) ----------
__device__ inline void acc_pack(unsigned u, float w, float& a, float& b){
    float2 f = __half22float2(__builtin_bit_cast(__half2, u));
    a = fmaf(w, f.x, a); b = fmaf(w, f.y, b);
}
__device__ inline void acc_row(float w, const uint4* rp, float* acc /*32*/){
    uint4 w0 = rp[0], w1 = rp[1], w2 = rp[2], w3 = rp[3];
    acc_pack(w0.x, w, acc[0],  acc[1]);  acc_pack(w0.y, w, acc[2],  acc[3]);
    acc_pack(w0.z, w, acc[4],  acc[5]);  acc_pack(w0.w, w, acc[6],  acc[7]);
    acc_pack(w1.x, w, acc[8],  acc[9]);  acc_pack(w1.y, w, acc[10], acc[11]);
    acc_pack(w1.z, w, acc[12], acc[13]); acc_pack(w1.w, w, acc[14], acc[15]);
    acc_pack(w2.x, w, acc[16], acc[17]); acc_pack(w2.y, w, acc[18], acc[19]);
    acc_pack(w2.z, w, acc[20], acc[21]); acc_pack(w2.w, w, acc[22], acc[23]);
    acc_pack(w3.x, w, acc[24], acc[25]); acc_pack(w3.y, w, acc[26], acc[27]);
    acc_pack(w3.z, w, acc[28], acc[29]); acc_pack(w3.w, w, acc[30], acc[31]);
}

// ---------- LDS overlay ----------
struct PartS {
    int hist[NB_BUCKETS]; int cntb[NB_BUCKETS];
    int cursor[NB_BUCKETS]; int copyBase[NB_BUCKETS];
    unsigned sorted[PART_CHUNK];
};                                             // 37512 B
struct BucketS {
    unsigned short sorted[CAP];                // 6 KB
    int hist[64]; int cursor[64]; int begs[64]; int cnts[64];
    float srow[64*28];                         // 7 KB
};                                             // 14336 B
struct MlpS { float Gs[784]; float prt[NTHR]; float h[128]; };  // 7.7 KB
union SMem { PartS part; BucketS bucket; MlpS mlp; };

__global__ __launch_bounds__(NTHR, 4) void k_mega(
        const float* __restrict__ x, const void* __restrict__ ei,
        const float* __restrict__ qw, const float* __restrict__ W1,
        const float* __restrict__ b1, const float* __restrict__ W2,
        const float* __restrict__ b2, float* __restrict__ outp,
        __half* __restrict__ z, unsigned* __restrict__ pairs,
        float* __restrict__ dinv, float4* __restrict__ cmat,
        float* __restrict__ G, int* __restrict__ bucketFill)
{
    __shared__ SMem U;
    __shared__ int is64_s;
    cg::grid_group grid = cg::this_grid();
    const int t = threadIdx.x, blk = blockIdx.x;

    // ================= phase 0: init (zero G/bucketFill, cmat) =================
    for (int i = blk*NTHR + t; i < GREP*784; i += NBLK*NTHR) G[i] = 0.f;
    for (int i = blk*NTHR + t; i < NB_BUCKETS; i += NBLK*NTHR) bucketFill[i] = 0;
    if (blk == 0 && t < 28){
        int p = t;
        int a = 0; { int rem = p, q = 0; while (rem >= 7 - q){ rem -= 7 - q; q++; } a = q; }
        C2 M00 = mkc(1,0), M01 = mkc(0,0), M10 = mkc(0,0), M11 = mkc(1,0);
        for (int k = 0; k < 6; k++){
            float th = 0.5f * qw[p*6 + k];
            float s, c; sincosf(th, &s, &c);
            C2 R00, R01, R10, R11;
            int type = k % 3;
            if (type == 0){      // Rx
                R00 = mkc(c,0); R01 = mkc(0,-s); R10 = mkc(0,-s); R11 = mkc(c,0);
            } else if (type == 1){ // Ry
                R00 = mkc(c,0); R01 = mkc(-s,0); R10 = mkc(s,0); R11 = mkc(c,0);
            } else {             // Rz
                R00 = mkc(c,-s); R01 = mkc(0,0); R10 = mkc(0,0); R11 = mkc(c,s);
            }
            C2 N00 = cadd(cmul(R00,M00), cmul(R01,M10));
            C2 N01 = cadd(cmul(R00,M01), cmul(R01,M11));
            C2 N10 = cadd(cmul(R10,M00), cmul(R11,M10));
            C2 N11 = cadd(cmul(R10,M01), cmul(R11,M11));
            M00=N00; M01=N01; M10=N10; M11=N11;
        }
        float B00  = (M00.x*M00.x + M00.y*M00.y) - (M10.x*M10.x + M10.y*M10.y);
        float B11  = (M01.x*M01.x + M01.y*M01.y) - (M11.x*M11.x + M11.y*M11.y);
        float B01r = (M00.x*M01.x + M00.y*M01.y) - (M10.x*M11.x + M10.y*M11.y);
        cmat[p] = make_float4(0.5f + 0.5f*B11, 0.5f*(B00 - B11), B01r, (float)a);
    }
    grid.sync();

    // ================= phase 1: partition (1 chunk per block) =================
    {
        if (t == 0) is64_s = 1;
        __syncthreads();
        if (t < 64){
            long long v = ((const long long*)ei)[t];
            if (v < 0 || v >= N_NODES) atomicAnd(&is64_s, 0);
        }
        __syncthreads();
        int is64 = is64_s;
        long long base = (long long)blk * PART_CHUNK;
        const int cnt = PART_CHUNK;                 // 256*6250 == N_EDGES exactly
        unsigned ds[EPT], sr[EPT];
        #pragma unroll
        for (int k = 0; k < EPT; k++){
            int i = t + NTHR*k;
            if (i < cnt){
                ds[k] = (unsigned)get_edge(ei, is64, (long long)N_EDGES + base + i);
                sr[k] = (unsigned)get_edge(ei, is64, base + i);
            } else ds[k] = 0xffffffffu;
        }
        if (t < NB_BUCKETS) U.part.hist[t] = 0;
        __syncthreads();
        #pragma unroll
        for (int k = 0; k < EPT; k++)
            if (ds[k] != 0xffffffffu) atomicAdd(&U.part.hist[ds[k] >> BSHIFT], 1);
        __syncthreads();
        if (t < NB_BUCKETS) U.part.cntb[t] = U.part.hist[t];
        __syncthreads();
        for (int ofs = 1; ofs < NB_BUCKETS; ofs <<= 1){   // inclusive scan
            int v = 0; bool a = t < NB_BUCKETS;
            if (a) v = U.part.hist[t] + (t >= ofs ? U.part.hist[t - ofs] : 0);
            __syncthreads();
            if (a) U.part.hist[t] = v;
            __syncthreads();
        }
        if (t < NB_BUCKETS){
            int cb = U.part.cntb[t];
            int ls = U.part.hist[t] - cb;                  // local exclusive start
            int gbase = t*CAP + atomicAdd(&bucketFill[t], cb);
            U.part.copyBase[t] = gbase - ls;
            U.part.cursor[t] = ls;
        }
        __syncthreads();
        #pragma unroll
        for (int k = 0; k < EPT; k++){
            if (ds[k] != 0xffffffffu){
                int pos = atomicAdd(&U.part.cursor[ds[k] >> BSHIFT], 1);
                U.part.sorted[pos] = (ds[k] << 16) | sr[k];
            }
        }
        __syncthreads();
        for (int i = t; i < cnt; i += NTHR){
            unsigned v = U.part.sorted[i];
            int b = (int)(v >> 22);                        // dst>>6
            pairs[U.part.copyBase[b] + i] = v;
        }
    }
    grid.sync();

    // ============ phase 2: degree pass (blk<64)  ||  features (blk>=64) ============
    if (blk < DEG_BLOCKS){
        for (int vb = blk; vb < NB_BUCKETS; vb += DEG_BLOCKS){
            if (t < 64) U.bucket.hist[t] = 0;
            __syncthreads();
            int s0 = vb*CAP;
            int cnt = bucketFill[vb]; if (cnt > CAP) cnt = CAP;
            for (int i = t; i < cnt; i += NTHR)
                atomicAdd(&U.bucket.hist[(pairs[s0 + i] >> 16) & 63], 1);
            __syncthreads();
            if (t < 64){
                int n = vb*64 + t;
                if (n < N_NODES) dinv[n] = rsqrtf((float)(U.bucket.hist[t] + 1));
            }
            __syncthreads();
        }
    } else {
        // quantum features: one wave per node, UNSCALED z (dinv applied in gather)
        int wv = t >> 6, lane = t & 63;
        int wid = (blk - DEG_BLOCKS)*16 + wv;
        const int WSTRIDE = (NBLK - DEG_BLOCKS)*16;        // 3072 waves
        for (int n = wid; n < N_NODES; n += WSTRIDE){
            const float4 v = ((const float4*)(x + (size_t)n*256))[lane];
            float persq = v.x*v.x + v.y*v.y + v.z*v.z + v.w*v.w;
            float red[15];
            red[0] = persq;
            red[1] = v.x*v.x + v.y*v.y;        // S0 qubit6
            red[2] = v.x*v.z + v.y*v.w;        // X qubit6
            {
                float px = dpp_mov<DPP_XOR1>(v.x), py = dpp_mov<DPP_XOR1>(v.y);
                float pz = dpp_mov<DPP_XOR1>(v.z), pw = dpp_mov<DPP_XOR1>(v.w);
                red[3] = v.x*px + v.y*py + v.z*pz + v.w*pw;
                red[9] = (lane & 1) ? 0.f : persq;
            }
            {
                float px = dpp_mov<DPP_XOR2>(v.x), py = dpp_mov<DPP_XOR2>(v.y);
                float pz = dpp_mov<DPP_XOR2>(v.z), pw = dpp_mov<DPP_XOR2>(v.w);
                red[4] = v.x*px + v.y*py + v.z*pz + v.w*pw;
                red[10] = (lane & 2) ? 0.f : persq;
            }
            #pragma unroll
            for (int j = 2; j < 6; j++){
                float px = __shfl_xor(v.x, 1 << j), py = __shfl_xor(v.y, 1 << j);
                float pz = __shfl_xor(v.z, 1 << j), pw = __shfl_xor(v.w, 1 << j);
                red[3 + j] = v.x*px + v.y*py + v.z*pz + v.w*pw;
                red[9 + j] = ((lane >> j) & 1) ? 0.0f : persq;
            }
            float S[15];
            #pragma unroll
            for (int k = 0; k < 15; k++) S[k] = lane63(wave_sum_dpp(red[k]));
            if (lane < 28){
                float4 cm = cmat[lane];
                int ap = (int)cm.w;
                float S0a = (ap==6) ? S[1] :
                            (ap==0 ? S[14] : ap==1 ? S[13] : ap==2 ? S[12] :
                             ap==3 ? S[11] : ap==4 ? S[10] : S[9]);
                float Xa  = (ap==6) ? S[2] :
                            0.5f*(ap==0 ? S[8] : ap==1 ? S[7] : ap==2 ? S[6] :
                                  ap==3 ? S[5] : ap==4 ? S[4] : S[3]);
                float feat = cm.x + (cm.y*S0a + cm.z*Xa) / S[0];
                z[(size_t)n*ZSTRIDE + lane] = __float2half(feat);
            } else if (lane < 32){
                z[(size_t)n*ZSTRIDE + lane] = __float2half(0.f);
            }
        }
    }
    grid.sync();

    // ===== phase 3: per-bucket LDS sort + weighted gather + relu + partial Gram =====
    for (int vb = blk; vb < NB_BUCKETS; vb += NBLK){
        int s0 = vb*CAP;
        int cnt = bucketFill[vb]; if (cnt > CAP) cnt = CAP;
        if (t < 64) U.bucket.hist[t] = 0;
        __syncthreads();
        for (int i = t; i < cnt; i += NTHR){
            unsigned v = pairs[s0 + i];
            atomicAdd(&U.bucket.hist[(v >> 16) & 63], 1);
        }
        __syncthreads();
        int mycnt = (t < 64) ? U.bucket.hist[t] : 0;
        for (int ofs = 1; ofs < 64; ofs <<= 1){
            int nv = 0;
            if (t < 64) nv = U.bucket.hist[t] + (t >= ofs ? U.bucket.hist[t - ofs] : 0);
            __syncthreads();
            if (t < 64) U.bucket.hist[t] = nv;
            __syncthreads();
        }
        if (t < 64){
            U.bucket.cursor[t] = U.bucket.hist[t] - mycnt;
            U.bucket.begs[t]   = U.bucket.hist[t] - mycnt;
            U.bucket.cnts[t]   = mycnt;
        }
        __syncthreads();
        for (int i = t; i < cnt; i += NTHR){
            unsigned v = pairs[s0 + i];
            int d = (v >> 16) & 63;
            int pos = atomicAdd(&U.bucket.cursor[d], 1);
            U.bucket.sorted[pos] = (unsigned short)(v & 0xffffu);
        }
        __syncthreads();

        // gather: 16 threads per node; weight each row by dinv[src]
        int d = t >> 4, sub = t & 15;
        int n = vb*64 + d;
        bool valid = n < N_NODES;
        float acc[32];
        #pragma unroll
        for (int k = 0; k < 32; k++) acc[k] = 0.f;
        if (valid){
            int beg = U.bucket.begs[d], end = beg + U.bucket.cnts[d];
            for (int i = beg + sub; i < end; i += 16){
                int src = U.bucket.sorted[i];
                acc_row(dinv[src], (const uint4*)(z + (size_t)src*ZSTRIDE), acc);
            }
            if (sub == 15)   // self loop, weight dinv[n]
                acc_row(dinv[n], (const uint4*)(z + (size_t)n*ZSTRIDE), acc);
        }
        #pragma unroll
        for (int k = 0; k < 32; k++){
            acc[k] += dpp_mov<DPP_XOR1>(acc[k]);   // xor 1
            acc[k] += dpp_mov<DPP_XOR2>(acc[k]);   // xor 2
            acc[k] += __shfl_xor(acc[k], 4);       // xor 4
            acc[k] += __shfl_xor(acc[k], 8);       // xor 8
        }
        if (sub == 0){
            float dv = valid ? dinv[n] : 0.f;
            #pragma unroll
            for (int k = 0; k < 28; k++)
                U.bucket.srow[d*28 + k] = fmaxf(acc[k]*dv, 0.f);
        }
        __syncthreads();

        // partial Gram: 2x2 register tiling, 196 threads, replica vb&15
        if (t < 196){
            float* Gr = G + (size_t)(vb & (GREP-1)) * 784;
            int ti = t / 14, tj = t % 14;
            int i0 = 2*ti, j0 = 2*tj;
            float c00 = 0.f, c01 = 0.f, c10 = 0.f, c11 = 0.f;
            for (int nn = 0; nn < 64; nn++){
                const float* r = U.bucket.srow + nn*28;
                float a0 = r[i0], a1 = r[i0+1], b0 = r[j0], b1 = r[j0+1];
                c00 += a0*b0; c01 += a0*b1; c10 += a1*b0; c11 += a1*b1;
            }
            atomicAdd(&Gr[(i0  )*28 + j0  ], c00);
            atomicAdd(&Gr[(i0  )*28 + j0+1], c01);
            atomicAdd(&Gr[(i0+1)*28 + j0  ], c10);
            atomicAdd(&Gr[(i0+1)*28 + j0+1], c11);
        }
        __syncthreads();
    }
    grid.sync();

    // ================= phase 4: MLP (block 0) =================
    if (blk == 0){
        for (int i = t; i < 784; i += NTHR){
            float s = 0.f;
            #pragma unroll
            for (int r = 0; r < GREP; r++) s += G[r*784 + i];
            U.mlp.Gs[i] = s;
        }
        __syncthreads();
        int j = t & 127, q = t >> 7;                       // q in 0..7, 98 elems each
        const float* w = W1 + (size_t)j*784 + q*98;
        const float* g = U.mlp.Gs + q*98;
        float s = 0.f;
        for (int i = 0; i < 98; i++) s += g[i] * w[i];
        U.mlp.prt[t] = s;
        __syncthreads();
        if (t < 128){
            float hv = b1[t];
            #pragma unroll
            for (int qq = 0; qq < 8; qq++) hv += U.mlp.prt[t + 128*qq];
            U.mlp.h[t] = fmaxf(hv, 0.f) * W2[t];
        }
        __syncthreads();
        for (int ofs = 64; ofs > 0; ofs >>= 1){
            if (t < ofs) U.mlp.h[t] += U.mlp.h[t + ofs];
            __syncthreads();
        }
        if (t == 0) outp[0] = 1.f / (1.f + expf(-(U.mlp.h[0] + b2[0])));
    }
}

extern "C" void kernel_launch(void* const* d_in, const int* in_sizes, int n_in,
                              void* d_out, int out_size, void* d_ws, size_t ws_size,
                              hipStream_t stream){
    const float* x  = (const float*)d_in[0];
    const void*  ei = d_in[1];
    const float* qw = (const float*)d_in[2];
    const float* W1 = (const float*)d_in[3];
    const float* b1 = (const float*)d_in[4];
    const float* W2 = (const float*)d_in[5];
    const float* b2 = (const float*)d_in[6];
    float* outp = (float*)d_out;

    char* base = (char*)d_ws;
    __half*   z     = (__half*)base;   base += (size_t)N_NODES*ZSTRIDE*2;   // 3.2 MB
    unsigned* pairs = (unsigned*)base; base += (size_t)NB_BUCKETS*CAP*4;    // 9.6 MB
    float*    dinv  = (float*)base;    base += (size_t)N_NODES*4;
    float4*   cmat  = (float4*)base;   base += 448;
    float*    G     = (float*)base;    base += GREP*784*4;                  // 50 KB
    int*      bucketFill = (int*)base; base += 4096;

    void* kargs[] = { (void*)&x, (void*)&ei, (void*)&qw, (void*)&W1, (void*)&b1,
                      (void*)&W2, (void*)&b2, (void*)&outp, (void*)&z, (void*)&pairs,
                      (void*)&dinv, (void*)&cmat, (void*)&G, (void*)&bucketFill };
    hipLaunchCooperativeKernel((const void*)k_mega, dim3(NBLK), dim3(NTHR),
                               kargs, 0, stream);
}

// Round 6
// 263.139 us; speedup vs baseline: 1.2316x; 1.2316x over previous
//
#include <hip/hip_runtime.h>
#include <hip/hip_fp16.h>
#include <math.h>

#define N_NODES 50000
#define N_EDGES 1600000
#define BSHIFT 6            // bucket = dst>>6 (64 nodes per bucket)
#define NB_BUCKETS 782      // ceil(50000/64)
#define PART_CHUNK 8192
#define NCHUNK 196          // ceil(N_EDGES / PART_CHUNK)
#define FEAT_BLOCKS 3125    // 50000 nodes / 16 waves per 1024-thr block
#define CAP 3072            // per-bucket slot stride; mean 2048, sigma ~45
#define ZSTRIDE 32          // z row = 32 halves = 64B, one cache line
#define GREP 16             // G replicas: avoids deep per-line atomic chains

// ---------- DPP helpers (VALU-pipe cross-lane, no LDS) ----------
template<int CTRL>
__device__ inline float dpp_mov(float x){
    return __int_as_float(__builtin_amdgcn_update_dpp(0, __float_as_int(x), CTRL, 0xf, 0xf, false));
}
__device__ inline float wave_sum_dpp(float x){
    x += dpp_mov<0x111>(x);   // row_shr:1
    x += dpp_mov<0x112>(x);   // row_shr:2
    x += dpp_mov<0x114>(x);   // row_shr:4
    x += dpp_mov<0x118>(x);   // row_shr:8
    x += dpp_mov<0x142>(x);   // row_bcast:15
    x += dpp_mov<0x143>(x);   // row_bcast:31
    return x;
}
__device__ inline float lane63(float x){
    return __int_as_float(__builtin_amdgcn_readlane(__float_as_int(x), 63));
}
#define DPP_XOR1 0xB1   // quad_perm [1,0,3,2]
#define DPP_XOR2 0x4E   // quad_perm [2,3,0,1]

// ---------- complex 2x2 helpers ----------
struct C2 { float x, y; };
__device__ inline C2 mkc(float x, float y){ C2 r; r.x=x; r.y=y; return r; }
__device__ inline C2 cmul(C2 a, C2 b){ return mkc(a.x*b.x - a.y*b.y, a.x*b.y + a.y*b.x); }
__device__ inline C2 cadd(C2 a, C2 b){ return mkc(a.x+b.x, a.y+b.y); }

// ---------- K0: probe dtype + pair coefficients + zero bucketFill/G/ticket ----------
__global__ __launch_bounds__(256) void k_init(const float* __restrict__ qw,
        const void* __restrict__ ei, float4* __restrict__ cmat,
        int* __restrict__ flag, int* __restrict__ bucketFill, float* __restrict__ G,
        int* __restrict__ ticket){
    int t = threadIdx.x;
    for (int i = t; i < NB_BUCKETS; i += 256) bucketFill[i] = 0;
    for (int i = t; i < GREP*784; i += 256) G[i] = 0.f;
    if (t == 0) ticket[0] = 0;
    if (t == 255){
        const long long* e64 = (const long long*)ei;
        int ok = 1;
        for (int i = 0; i < 64; i++){
            long long v = e64[i];
            if (v < 0 || v >= N_NODES) ok = 0;
        }
        flag[0] = ok;
    }
    if (t < 28){
        int p = t;
        int a = 0; { int rem = p, q = 0; while (rem >= 7 - q){ rem -= 7 - q; q++; } a = q; }
        C2 M00 = mkc(1,0), M01 = mkc(0,0), M10 = mkc(0,0), M11 = mkc(1,0);
        for (int k = 0; k < 6; k++){
            float th = 0.5f * qw[p*6 + k];
            float s, c; sincosf(th, &s, &c);
            C2 R00, R01, R10, R11;
            int type = k % 3;
            if (type == 0){      // Rx
                R00 = mkc(c,0); R01 = mkc(0,-s); R10 = mkc(0,-s); R11 = mkc(c,0);
            } else if (type == 1){ // Ry
                R00 = mkc(c,0); R01 = mkc(-s,0); R10 = mkc(s,0); R11 = mkc(c,0);
            } else {             // Rz
                R00 = mkc(c,-s); R01 = mkc(0,0); R10 = mkc(0,0); R11 = mkc(c,s);
            }
            C2 N00 = cadd(cmul(R00,M00), cmul(R01,M10));
            C2 N01 = cadd(cmul(R00,M01), cmul(R01,M11));
            C2 N10 = cadd(cmul(R10,M00), cmul(R11,M10));
            C2 N11 = cadd(cmul(R10,M01), cmul(R11,M11));
            M00=N00; M01=N01; M10=N10; M11=N11;
        }
        float B00  = (M00.x*M00.x + M00.y*M00.y) - (M10.x*M10.x + M10.y*M10.y);
        float B11  = (M01.x*M01.x + M01.y*M01.y) - (M11.x*M11.x + M11.y*M11.y);
        float B01r = (M00.x*M01.x + M00.y*M01.y) - (M10.x*M11.x + M10.y*M11.y);
        cmat[p] = make_float4(0.5f + 0.5f*B11, 0.5f*(B00 - B11), B01r, (float)a);
    }
}

__device__ inline int get_edge(const void* ei, int is64, long long idx){
    if (is64) return (int)((const long long*)ei)[idx];
    return ((const int*)ei)[idx];
}

// ---------- dual-role: partition (blocks < NCHUNK) || features (rest) ----------
// feat needs only cmat (z is stored UNSCALED; dinv applied in the gather),
// so both roles run concurrently in one launch at full occupancy.
struct PartS {
    int hist[NB_BUCKETS]; int cntb[NB_BUCKETS];
    int cursor[NB_BUCKETS]; int copyBase[NB_BUCKETS];
    unsigned sorted[PART_CHUNK];
};                                             // 37.5 KB (2 blocks/CU fits)

__global__ __launch_bounds__(1024) void k_partfeat(
        const float* __restrict__ x, const void* __restrict__ ei,
        const int* __restrict__ flag, int* __restrict__ bucketFill,
        unsigned* __restrict__ pairs, const float4* __restrict__ cmat,
        __half* __restrict__ z){
    __shared__ PartS P;
    int tid = threadIdx.x;
    if (blockIdx.x < NCHUNK){
        // ---------------- partition role (round-4 k_part body) ----------------
        int c = blockIdx.x;
        long long base = (long long)c * PART_CHUNK;
        int cnt = (int)((N_EDGES - base < PART_CHUNK) ? (N_EDGES - base) : PART_CHUNK);
        int is64 = flag[0];
        unsigned ds[8], sr[8];
        #pragma unroll
        for (int k = 0; k < 8; k++){
            int i = tid + 1024*k;
            if (i < cnt){
                ds[k] = (unsigned)get_edge(ei, is64, (long long)N_EDGES + base + i);
                sr[k] = (unsigned)get_edge(ei, is64, base + i);
            } else ds[k] = 0xffffffffu;
        }
        if (tid < NB_BUCKETS) P.hist[tid] = 0;
        __syncthreads();
        #pragma unroll
        for (int k = 0; k < 8; k++)
            if (ds[k] != 0xffffffffu) atomicAdd(&P.hist[ds[k] >> BSHIFT], 1);
        __syncthreads();
        if (tid < NB_BUCKETS) P.cntb[tid] = P.hist[tid];
        __syncthreads();
        for (int ofs = 1; ofs < NB_BUCKETS; ofs <<= 1){   // inclusive scan
            int v = 0; bool a = tid < NB_BUCKETS;
            if (a) v = P.hist[tid] + (tid >= ofs ? P.hist[tid - ofs] : 0);
            __syncthreads();
            if (a) P.hist[tid] = v;
            __syncthreads();
        }
        if (tid < NB_BUCKETS){
            int cb = P.cntb[tid];
            int ls = P.hist[tid] - cb;                     // local exclusive start
            int gbase = tid*CAP + atomicAdd(&bucketFill[tid], cb);
            P.copyBase[tid] = gbase - ls;
            P.cursor[tid] = ls;
        }
        __syncthreads();
        #pragma unroll
        for (int k = 0; k < 8; k++){
            if (ds[k] != 0xffffffffu){
                int pos = atomicAdd(&P.cursor[ds[k] >> BSHIFT], 1);
                P.sorted[pos] = (ds[k] << 16) | sr[k];
            }
        }
        __syncthreads();
        for (int i = tid; i < cnt; i += 1024){
            unsigned v = P.sorted[i];
            int b = (int)(v >> 22);                        // dst>>6
            pairs[P.copyBase[b] + i] = v;
        }
    } else {
        // ---------------- feature role: one wave per node, UNSCALED z ----------------
        int wv = tid >> 6, lane = tid & 63;
        int n = (blockIdx.x - NCHUNK)*16 + wv;
        if (n < N_NODES){
            const float4 v = ((const float4*)(x + (size_t)n*256))[lane];
            float persq = v.x*v.x + v.y*v.y + v.z*v.z + v.w*v.w;
            float red[15];
            red[0] = persq;
            red[1] = v.x*v.x + v.y*v.y;        // S0 qubit6
            red[2] = v.x*v.z + v.y*v.w;        // X qubit6
            {
                float px = dpp_mov<DPP_XOR1>(v.x), py = dpp_mov<DPP_XOR1>(v.y);
                float pz = dpp_mov<DPP_XOR1>(v.z), pw = dpp_mov<DPP_XOR1>(v.w);
                red[3] = v.x*px + v.y*py + v.z*pz + v.w*pw;
                red[9] = (lane & 1) ? 0.f : persq;
            }
            {
                float px = dpp_mov<DPP_XOR2>(v.x), py = dpp_mov<DPP_XOR2>(v.y);
                float pz = dpp_mov<DPP_XOR2>(v.z), pw = dpp_mov<DPP_XOR2>(v.w);
                red[4] = v.x*px + v.y*py + v.z*pz + v.w*pw;
                red[10] = (lane & 2) ? 0.f : persq;
            }
            #pragma unroll
            for (int j = 2; j < 6; j++){
                float px = __shfl_xor(v.x, 1 << j), py = __shfl_xor(v.y, 1 << j);
                float pz = __shfl_xor(v.z, 1 << j), pw = __shfl_xor(v.w, 1 << j);
                red[3 + j] = v.x*px + v.y*py + v.z*pz + v.w*pw;
                red[9 + j] = ((lane >> j) & 1) ? 0.0f : persq;
            }
            float S[15];
            #pragma unroll
            for (int k = 0; k < 15; k++) S[k] = lane63(wave_sum_dpp(red[k]));
            if (lane < 28){
                float4 cm = cmat[lane];
                int ap = (int)cm.w;
                float S0a = (ap==6) ? S[1] :
                            (ap==0 ? S[14] : ap==1 ? S[13] : ap==2 ? S[12] :
                             ap==3 ? S[11] : ap==4 ? S[10] : S[9]);
                float Xa  = (ap==6) ? S[2] :
                            0.5f*(ap==0 ? S[8] : ap==1 ? S[7] : ap==2 ? S[6] :
                                  ap==3 ? S[5] : ap==4 ? S[4] : S[3]);
                float feat = cm.x + (cm.y*S0a + cm.z*Xa) / S[0];
                z[(size_t)n*ZSTRIDE + lane] = __float2half(feat);
            } else if (lane < 32){
                z[(size_t)n*ZSTRIDE + lane] = __float2half(0.f);
            }
        }
    }
}

// ---------- slim degree pass: per-bucket hist only -> dinv ----------
__global__ __launch_bounds__(256) void k_deg(const unsigned* __restrict__ pairs,
        const int* __restrict__ bucketFill, float* __restrict__ dinv){
    __shared__ int hist[64];
    int b = blockIdx.x, t = threadIdx.x;
    int s0 = b*CAP;
    int cnt = bucketFill[b];
    if (cnt > CAP) cnt = CAP;
    if (t < 64) hist[t] = 0;
    __syncthreads();
    for (int i = t; i < cnt; i += 256)
        atomicAdd(&hist[(pairs[s0 + i] >> 16) & 63], 1);
    __syncthreads();
    if (t < 64){
        int n = b*64 + t;
        if (n < N_NODES) dinv[n] = rsqrtf((float)(hist[t] + 1));
    }
}

// ---------- fused per-bucket: LDS sort + weighted gather + relu + Gram + MLP ----------
__device__ inline void acc_pack(unsigned u, float w, float& a, float& b){
    float2 f = __half22float2(__builtin_bit_cast(__half2, u));
    a = fmaf(w, f.x, a); b = fmaf(w, f.y, b);
}
__device__ inline void acc_row(float w, const uint4* rp, float* acc /*32*/){
    uint4 w0 = rp[0], w1 = rp[1], w2 = rp[2], w3 = rp[3];
    acc_pack(w0.x, w, acc[0],  acc[1]);  acc_pack(w0.y, w, acc[2],  acc[3]);
    acc_pack(w0.z, w, acc[4],  acc[5]);  acc_pack(w0.w, w, acc[6],  acc[7]);
    acc_pack(w1.x, w, acc[8],  acc[9]);  acc_pack(w1.y, w, acc[10], acc[11]);
    acc_pack(w1.z, w, acc[12], acc[13]); acc_pack(w1.w, w, acc[14], acc[15]);
    acc_pack(w2.x, w, acc[16], acc[17]); acc_pack(w2.y, w, acc[18], acc[19]);
    acc_pack(w2.z, w, acc[20], acc[21]); acc_pack(w2.w, w, acc[22], acc[23]);
    acc_pack(w3.x, w, acc[24], acc[25]); acc_pack(w3.y, w, acc[26], acc[27]);
    acc_pack(w3.z, w, acc[28], acc[29]); acc_pack(w3.w, w, acc[30], acc[31]);
}

struct BucketS {
    unsigned short sorted[CAP];                // 6 KB
    int hist[64]; int cursor[64]; int begs[64]; int cnts[64];
    float srow[64*28];                         // 7 KB
};
struct MlpS { float Gs[784]; float prt[512]; float h[128]; };  // 5.7 KB
union BSMem { BucketS b; MlpS m; };

__global__ __launch_bounds__(512) void k_bucket(const unsigned* __restrict__ pairs,
        const int* __restrict__ bucketFill, const __half* __restrict__ z,
        const float* __restrict__ dinv, float* __restrict__ G,
        int* __restrict__ ticket,
        const float* __restrict__ W1, const float* __restrict__ b1,
        const float* __restrict__ W2, const float* __restrict__ b2,
        float* __restrict__ outp){
    __shared__ BSMem U;
    __shared__ int lastS;
    int b = blockIdx.x, t = threadIdx.x;
    int s0 = b*CAP;
    int cnt = bucketFill[b];
    if (cnt > CAP) cnt = CAP;
    if (t < 64) U.b.hist[t] = 0;
    __syncthreads();
    for (int i = t; i < cnt; i += 512){
        unsigned v = pairs[s0 + i];
        atomicAdd(&U.b.hist[(v >> 16) & 63], 1);
    }
    __syncthreads();
    int mycnt = (t < 64) ? U.b.hist[t] : 0;
    for (int ofs = 1; ofs < 64; ofs <<= 1){
        int nv = 0;
        if (t < 64) nv = U.b.hist[t] + (t >= ofs ? U.b.hist[t - ofs] : 0);
        __syncthreads();
        if (t < 64) U.b.hist[t] = nv;
        __syncthreads();
    }
    if (t < 64){
        U.b.cursor[t] = U.b.hist[t] - mycnt;
        U.b.begs[t]   = U.b.hist[t] - mycnt;
        U.b.cnts[t]   = mycnt;
    }
    __syncthreads();
    for (int i = t; i < cnt; i += 512){
        unsigned v = pairs[s0 + i];
        int d = (v >> 16) & 63;
        int pos = atomicAdd(&U.b.cursor[d], 1);
        U.b.sorted[pos] = (unsigned short)(v & 0xffffu);
    }
    __syncthreads();

    // gather: 8 threads per node; each row weighted by dinv[src] (z unscaled)
    int d = t >> 3, sub = t & 7;
    int n = b*64 + d;
    bool valid = n < N_NODES;
    float acc[32];
    #pragma unroll
    for (int k = 0; k < 32; k++) acc[k] = 0.f;
    if (valid){
        int beg = U.b.begs[d], end = beg + U.b.cnts[d];
        for (int i = beg + sub; i < end; i += 8){
            int src = U.b.sorted[i];
            acc_row(dinv[src], (const uint4*)(z + (size_t)src*ZSTRIDE), acc);
        }
        if (sub == 7)   // self loop, weight dinv[n]
            acc_row(dinv[n], (const uint4*)(z + (size_t)n*ZSTRIDE), acc);
    }
    #pragma unroll
    for (int k = 0; k < 32; k++){
        acc[k] += dpp_mov<DPP_XOR1>(acc[k]);   // xor 1
        acc[k] += dpp_mov<DPP_XOR2>(acc[k]);   // xor 2
        acc[k] += __shfl_xor(acc[k], 4);       // xor 4
    }
    if (sub == 0){
        float dv = valid ? dinv[n] : 0.f;
        #pragma unroll
        for (int k = 0; k < 28; k++)
            U.b.srow[d*28 + k] = fmaxf(acc[k]*dv, 0.f);   // zeros for invalid rows
    }
    __syncthreads();

    // partial Gram: 2x2 register tiling, 196 threads, replica b&15
    if (t < 196){
        float* Gr = G + (size_t)(b & (GREP-1)) * 784;
        int ti = t / 14, tj = t % 14;
        int i0 = 2*ti, j0 = 2*tj;
        float c00 = 0.f, c01 = 0.f, c10 = 0.f, c11 = 0.f;
        for (int nn = 0; nn < 64; nn++){
            const float* r = U.b.srow + nn*28;
            float a0 = r[i0], a1 = r[i0+1], b0 = r[j0], b1 = r[j0+1];
            c00 += a0*b0; c01 += a0*b1; c10 += a1*b0; c11 += a1*b1;
        }
        atomicAdd(&Gr[(i0  )*28 + j0  ], c00);
        atomicAdd(&Gr[(i0  )*28 + j0+1], c01);
        atomicAdd(&Gr[(i0+1)*28 + j0  ], c10);
        atomicAdd(&Gr[(i0+1)*28 + j0+1], c11);
    }

    // ---- last finished block runs the MLP (saves a launch + gap) ----
    __threadfence();                 // make this block's G atomics visible
    __syncthreads();                 // all threads' atomics drained (vmcnt=0)
    if (t == 0) lastS = atomicAdd(ticket, 1);
    __syncthreads();
    if (lastS != NB_BUCKETS - 1) return;

    // agent-scope loads: G was written by device-scope atomics from other XCDs;
    // plain loads could hit a stale local-L2 line (zeros from k_init).
    for (int i = t; i < 784; i += 512){
        float s = 0.f;
        #pragma unroll
        for (int r = 0; r < GREP; r++)
            s += __hip_atomic_load(&G[r*784 + i], __ATOMIC_RELAXED, __HIP_MEMORY_SCOPE_AGENT);
        U.m.Gs[i] = s;
    }
    __syncthreads();
    int j = t & 127, q = t >> 7;                   // q in 0..3, 196 elems each
    const float* w = W1 + (size_t)j*784 + q*196;
    const float* g = U.m.Gs + q*196;
    float s = 0.f;
    for (int i = 0; i < 196; i++) s += g[i] * w[i];
    U.m.prt[t] = s;
    __syncthreads();
    if (t < 128){
        float hv = U.m.prt[t] + U.m.prt[t+128] + U.m.prt[t+256] + U.m.prt[t+384] + b1[t];
        U.m.h[t] = fmaxf(hv, 0.f) * W2[t];
    }
    __syncthreads();
    for (int ofs = 64; ofs > 0; ofs >>= 1){
        if (t < ofs) U.m.h[t] += U.m.h[t + ofs];
        __syncthreads();
    }
    if (t == 0) outp[0] = 1.f / (1.f + expf(-(U.m.h[0] + b2[0])));
}

extern "C" void kernel_launch(void* const* d_in, const int* in_sizes, int n_in,
                              void* d_out, int out_size, void* d_ws, size_t ws_size,
                              hipStream_t stream){
    const float* x  = (const float*)d_in[0];
    const void*  ei = d_in[1];
    const float* qw = (const float*)d_in[2];
    const float* W1 = (const float*)d_in[3];
    const float* b1 = (const float*)d_in[4];
    const float* W2 = (const float*)d_in[5];
    const float* b2 = (const float*)d_in[6];
    float* outp = (float*)d_out;

    char* base = (char*)d_ws;
    __half*   z     = (__half*)base;   base += (size_t)N_NODES*ZSTRIDE*2;   // 3.2 MB
    unsigned* pairs = (unsigned*)base; base += (size_t)NB_BUCKETS*CAP*4;    // 9.6 MB
    float*    dinv  = (float*)base;    base += (size_t)N_NODES*4;
    float4*   cmat  = (float4*)base;   base += 448;
    float*    G     = (float*)base;    base += GREP*784*4;                  // 50 KB
    int*      bucketFill = (int*)base; base += 4096;
    int*      flag  = (int*)base;      base += 16;
    int*      ticket = (int*)base;     base += 16;

    k_init<<<1, 256, 0, stream>>>(qw, ei, cmat, flag, bucketFill, G, ticket);
    k_partfeat<<<NCHUNK + FEAT_BLOCKS, 1024, 0, stream>>>(x, ei, flag, bucketFill, pairs, cmat, z);
    k_deg<<<NB_BUCKETS, 256, 0, stream>>>(pairs, bucketFill, dinv);
    k_bucket<<<NB_BUCKETS, 512, 0, stream>>>(pairs, bucketFill, z, dinv, G, ticket,
                                             W1, b1, W2, b2, outp);
}

// Round 7
// 171.272 us; speedup vs baseline: 1.8922x; 1.5364x over previous
//
#include <hip/hip_runtime.h>
#include <hip/hip_fp16.h>
#include <math.h>

#define N_NODES 50000
#define N_EDGES 1600000
#define BSHIFT 6            // bucket = dst>>6 (64 nodes per bucket)
#define NB_BUCKETS 782      // ceil(50000/64)
#define PART_CHUNK 8192
#define NCHUNK 196          // ceil(N_EDGES / PART_CHUNK)
#define FEAT_BLOCKS 3125    // 50000 nodes / 16 waves per 1024-thr block
#define CAP 3072            // per-bucket slot stride; mean 2048, sigma ~45
#define ZSTRIDE 32          // z row = 32 halves = 64B, one cache line
#define GREP 16             // G replicas: avoids deep per-line atomic chains

// ---------- DPP helpers (VALU-pipe cross-lane, no LDS) ----------
template<int CTRL>
__device__ inline float dpp_mov(float x){
    return __int_as_float(__builtin_amdgcn_update_dpp(0, __float_as_int(x), CTRL, 0xf, 0xf, false));
}
__device__ inline float wave_sum_dpp(float x){
    x += dpp_mov<0x111>(x);   // row_shr:1
    x += dpp_mov<0x112>(x);   // row_shr:2
    x += dpp_mov<0x114>(x);   // row_shr:4
    x += dpp_mov<0x118>(x);   // row_shr:8
    x += dpp_mov<0x142>(x);   // row_bcast:15
    x += dpp_mov<0x143>(x);   // row_bcast:31
    return x;
}
__device__ inline float lane63(float x){
    return __int_as_float(__builtin_amdgcn_readlane(__float_as_int(x), 63));
}
#define DPP_XOR1 0xB1   // quad_perm [1,0,3,2]
#define DPP_XOR2 0x4E   // quad_perm [2,3,0,1]

// ---------- complex 2x2 helpers ----------
struct C2 { float x, y; };
__device__ inline C2 mkc(float x, float y){ C2 r; r.x=x; r.y=y; return r; }
__device__ inline C2 cmul(C2 a, C2 b){ return mkc(a.x*b.x - a.y*b.y, a.x*b.y + a.y*b.x); }
__device__ inline C2 cadd(C2 a, C2 b){ return mkc(a.x+b.x, a.y+b.y); }

// ---------- K0: probe dtype + pair coefficients + zero bucketFill/G ----------
__global__ __launch_bounds__(256) void k_init(const float* __restrict__ qw,
        const void* __restrict__ ei, float4* __restrict__ cmat,
        int* __restrict__ flag, int* __restrict__ bucketFill, float* __restrict__ G){
    int t = threadIdx.x;
    for (int i = t; i < NB_BUCKETS; i += 256) bucketFill[i] = 0;
    for (int i = t; i < GREP*784; i += 256) G[i] = 0.f;
    if (t == 255){
        const long long* e64 = (const long long*)ei;
        int ok = 1;
        for (int i = 0; i < 64; i++){
            long long v = e64[i];
            if (v < 0 || v >= N_NODES) ok = 0;
        }
        flag[0] = ok;
    }
    if (t < 28){
        int p = t;
        int a = 0; { int rem = p, q = 0; while (rem >= 7 - q){ rem -= 7 - q; q++; } a = q; }
        C2 M00 = mkc(1,0), M01 = mkc(0,0), M10 = mkc(0,0), M11 = mkc(1,0);
        for (int k = 0; k < 6; k++){
            float th = 0.5f * qw[p*6 + k];
            float s, c; sincosf(th, &s, &c);
            C2 R00, R01, R10, R11;
            int type = k % 3;
            if (type == 0){      // Rx
                R00 = mkc(c,0); R01 = mkc(0,-s); R10 = mkc(0,-s); R11 = mkc(c,0);
            } else if (type == 1){ // Ry
                R00 = mkc(c,0); R01 = mkc(-s,0); R10 = mkc(s,0); R11 = mkc(c,0);
            } else {             // Rz
                R00 = mkc(c,-s); R01 = mkc(0,0); R10 = mkc(0,0); R11 = mkc(c,s);
            }
            C2 N00 = cadd(cmul(R00,M00), cmul(R01,M10));
            C2 N01 = cadd(cmul(R00,M01), cmul(R01,M11));
            C2 N10 = cadd(cmul(R10,M00), cmul(R11,M10));
            C2 N11 = cadd(cmul(R10,M01), cmul(R11,M11));
            M00=N00; M01=N01; M10=N10; M11=N11;
        }
        float B00  = (M00.x*M00.x + M00.y*M00.y) - (M10.x*M10.x + M10.y*M10.y);
        float B11  = (M01.x*M01.x + M01.y*M01.y) - (M11.x*M11.x + M11.y*M11.y);
        float B01r = (M00.x*M01.x + M00.y*M01.y) - (M10.x*M11.x + M10.y*M11.y);
        cmat[p] = make_float4(0.5f + 0.5f*B11, 0.5f*(B00 - B11), B01r, (float)a);
    }
}

__device__ inline int get_edge(const void* ei, int is64, long long idx){
    if (is64) return (int)((const long long*)ei)[idx];
    return ((const int*)ei)[idx];
}

// ---------- dual-role: partition (blocks < NCHUNK) || features (rest) ----------
// feat needs only cmat (z written UNSCALED here; k_degscale premultiplies it by
// dinv afterwards), so both roles run concurrently in one launch.
struct PartS {
    int hist[NB_BUCKETS]; int cntb[NB_BUCKETS];
    int cursor[NB_BUCKETS]; int copyBase[NB_BUCKETS];
    unsigned sorted[PART_CHUNK];
};                                             // 37.5 KB (2 blocks/CU fits)

__global__ __launch_bounds__(1024) void k_partfeat(
        const float* __restrict__ x, const void* __restrict__ ei,
        const int* __restrict__ flag, int* __restrict__ bucketFill,
        unsigned* __restrict__ pairs, const float4* __restrict__ cmat,
        __half* __restrict__ z){
    __shared__ PartS P;
    int tid = threadIdx.x;
    if (blockIdx.x < NCHUNK){
        // ---------------- partition role ----------------
        int c = blockIdx.x;
        long long base = (long long)c * PART_CHUNK;
        int cnt = (int)((N_EDGES - base < PART_CHUNK) ? (N_EDGES - base) : PART_CHUNK);
        int is64 = flag[0];
        unsigned ds[8], sr[8];
        #pragma unroll
        for (int k = 0; k < 8; k++){
            int i = tid + 1024*k;
            if (i < cnt){
                ds[k] = (unsigned)get_edge(ei, is64, (long long)N_EDGES + base + i);
                sr[k] = (unsigned)get_edge(ei, is64, base + i);
            } else ds[k] = 0xffffffffu;
        }
        if (tid < NB_BUCKETS) P.hist[tid] = 0;
        __syncthreads();
        #pragma unroll
        for (int k = 0; k < 8; k++)
            if (ds[k] != 0xffffffffu) atomicAdd(&P.hist[ds[k] >> BSHIFT], 1);
        __syncthreads();
        if (tid < NB_BUCKETS) P.cntb[tid] = P.hist[tid];
        __syncthreads();
        for (int ofs = 1; ofs < NB_BUCKETS; ofs <<= 1){   // inclusive scan
            int v = 0; bool a = tid < NB_BUCKETS;
            if (a) v = P.hist[tid] + (tid >= ofs ? P.hist[tid - ofs] : 0);
            __syncthreads();
            if (a) P.hist[tid] = v;
            __syncthreads();
        }
        if (tid < NB_BUCKETS){
            int cb = P.cntb[tid];
            int ls = P.hist[tid] - cb;                     // local exclusive start
            int gbase = tid*CAP + atomicAdd(&bucketFill[tid], cb);
            P.copyBase[tid] = gbase - ls;
            P.cursor[tid] = ls;
        }
        __syncthreads();
        #pragma unroll
        for (int k = 0; k < 8; k++){
            if (ds[k] != 0xffffffffu){
                int pos = atomicAdd(&P.cursor[ds[k] >> BSHIFT], 1);
                P.sorted[pos] = (ds[k] << 16) | sr[k];
            }
        }
        __syncthreads();
        for (int i = tid; i < cnt; i += 1024){
            unsigned v = P.sorted[i];
            int b = (int)(v >> 22);                        // dst>>6
            pairs[P.copyBase[b] + i] = v;
        }
    } else {
        // ---------------- feature role: one wave per node, UNSCALED z ----------------
        int wv = tid >> 6, lane = tid & 63;
        int n = (blockIdx.x - NCHUNK)*16 + wv;
        if (n < N_NODES){
            const float4 v = ((const float4*)(x + (size_t)n*256))[lane];
            float persq = v.x*v.x + v.y*v.y + v.z*v.z + v.w*v.w;
            float red[15];
            red[0] = persq;
            red[1] = v.x*v.x + v.y*v.y;        // S0 qubit6
            red[2] = v.x*v.z + v.y*v.w;        // X qubit6
            {
                float px = dpp_mov<DPP_XOR1>(v.x), py = dpp_mov<DPP_XOR1>(v.y);
                float pz = dpp_mov<DPP_XOR1>(v.z), pw = dpp_mov<DPP_XOR1>(v.w);
                red[3] = v.x*px + v.y*py + v.z*pz + v.w*pw;
                red[9] = (lane & 1) ? 0.f : persq;
            }
            {
                float px = dpp_mov<DPP_XOR2>(v.x), py = dpp_mov<DPP_XOR2>(v.y);
                float pz = dpp_mov<DPP_XOR2>(v.z), pw = dpp_mov<DPP_XOR2>(v.w);
                red[4] = v.x*px + v.y*py + v.z*pz + v.w*pw;
                red[10] = (lane & 2) ? 0.f : persq;
            }
            #pragma unroll
            for (int j = 2; j < 6; j++){
                float px = __shfl_xor(v.x, 1 << j), py = __shfl_xor(v.y, 1 << j);
                float pz = __shfl_xor(v.z, 1 << j), pw = __shfl_xor(v.w, 1 << j);
                red[3 + j] = v.x*px + v.y*py + v.z*pz + v.w*pw;
                red[9 + j] = ((lane >> j) & 1) ? 0.0f : persq;
            }
            float S[15];
            #pragma unroll
            for (int k = 0; k < 15; k++) S[k] = lane63(wave_sum_dpp(red[k]));
            if (lane < 28){
                float4 cm = cmat[lane];
                int ap = (int)cm.w;
                float S0a = (ap==6) ? S[1] :
                            (ap==0 ? S[14] : ap==1 ? S[13] : ap==2 ? S[12] :
                             ap==3 ? S[11] : ap==4 ? S[10] : S[9]);
                float Xa  = (ap==6) ? S[2] :
                            0.5f*(ap==0 ? S[8] : ap==1 ? S[7] : ap==2 ? S[6] :
                                  ap==3 ? S[5] : ap==4 ? S[4] : S[3]);
                float feat = cm.x + (cm.y*S0a + cm.z*Xa) / S[0];
                z[(size_t)n*ZSTRIDE + lane] = __float2half(feat);
            } else if (lane < 32){
                z[(size_t)n*ZSTRIDE + lane] = __float2half(0.f);
            }
        }
    }
}

// ---------- degree + in-place z scale: hist -> dinv, then z[n] *= dinv[n] ----------
__global__ __launch_bounds__(256) void k_degscale(const unsigned* __restrict__ pairs,
        const int* __restrict__ bucketFill, float* __restrict__ dinv,
        __half* __restrict__ z){
    __shared__ int hist[64];
    __shared__ float sdv[64];
    int b = blockIdx.x, t = threadIdx.x;
    int s0 = b*CAP;
    int cnt = bucketFill[b];
    if (cnt > CAP) cnt = CAP;
    if (t < 64) hist[t] = 0;
    __syncthreads();
    for (int i = t; i < cnt; i += 256)
        atomicAdd(&hist[(pairs[s0 + i] >> 16) & 63], 1);
    __syncthreads();
    if (t < 64){
        int n = b*64 + t;
        float dv = rsqrtf((float)(hist[t] + 1));
        sdv[t] = dv;
        if (n < N_NODES) dinv[n] = dv;
    }
    __syncthreads();
    // scale this bucket's 64 rows (16 half2 per row), coalesced
    __half2* zp = (__half2*)z + (size_t)b*64*(ZSTRIDE/2);
    for (int i = t; i < 64*(ZSTRIDE/2); i += 256){
        int d = i >> 4;
        if (b*64 + d < N_NODES){
            float2 f = __half22float2(zp[i]);
            float dv = sdv[d];
            zp[i] = __floats2half2_rn(f.x*dv, f.y*dv);
        }
    }
}

// ---------- fused per-bucket: LDS sort + gather (8 thr/node) + relu + Gram ----------
// (round-4 proven body: premultiplied z, unweighted accumulate, NO fence)
__device__ inline void acc_pack(unsigned u, float& a, float& b){
    float2 f = __half22float2(__builtin_bit_cast(__half2, u));
    a += f.x; b += f.y;
}
__device__ inline void acc_row(const uint4* rp, float* acc /*32*/){
    uint4 w0 = rp[0], w1 = rp[1], w2 = rp[2], w3 = rp[3];
    acc_pack(w0.x, acc[0],  acc[1]);  acc_pack(w0.y, acc[2],  acc[3]);
    acc_pack(w0.z, acc[4],  acc[5]);  acc_pack(w0.w, acc[6],  acc[7]);
    acc_pack(w1.x, acc[8],  acc[9]);  acc_pack(w1.y, acc[10], acc[11]);
    acc_pack(w1.z, acc[12], acc[13]); acc_pack(w1.w, acc[14], acc[15]);
    acc_pack(w2.x, acc[16], acc[17]); acc_pack(w2.y, acc[18], acc[19]);
    acc_pack(w2.z, acc[20], acc[21]); acc_pack(w2.w, acc[22], acc[23]);
    acc_pack(w3.x, acc[24], acc[25]); acc_pack(w3.y, acc[26], acc[27]);
    acc_pack(w3.z, acc[28], acc[29]); acc_pack(w3.w, acc[30], acc[31]);
}

__global__ __launch_bounds__(512) void k_bucket(const unsigned* __restrict__ pairs,
        const int* __restrict__ bucketFill, const __half* __restrict__ z,
        const float* __restrict__ dinv, float* __restrict__ G){
    __shared__ unsigned short sorted[CAP];     // 6 KB
    __shared__ int hist[64];
    __shared__ int cursor[64];
    __shared__ int begs[64];
    __shared__ int cnts[64];
    __shared__ float srow[64*28];              // 7 KB relu'd rows for Gram
    int b = blockIdx.x, t = threadIdx.x;
    int s0 = b*CAP;
    int cnt = bucketFill[b];
    if (cnt > CAP) cnt = CAP;
    if (t < 64) hist[t] = 0;
    __syncthreads();
    for (int i = t; i < cnt; i += 512){
        unsigned v = pairs[s0 + i];
        atomicAdd(&hist[(v >> 16) & 63], 1);
    }
    __syncthreads();
    int mycnt = (t < 64) ? hist[t] : 0;
    for (int ofs = 1; ofs < 64; ofs <<= 1){
        int nv = 0;
        if (t < 64) nv = hist[t] + (t >= ofs ? hist[t - ofs] : 0);
        __syncthreads();
        if (t < 64) hist[t] = nv;
        __syncthreads();
    }
    if (t < 64){
        cursor[t] = hist[t] - mycnt;
        begs[t]   = hist[t] - mycnt;
        cnts[t]   = mycnt;
    }
    __syncthreads();
    for (int i = t; i < cnt; i += 512){
        unsigned v = pairs[s0 + i];
        int d = (v >> 16) & 63;
        int pos = atomicAdd(&cursor[d], 1);
        sorted[pos] = (unsigned short)(v & 0xffffu);
    }
    __syncthreads();

    // gather: 8 threads per node
    int d = t >> 3, sub = t & 7;
    int n = b*64 + d;
    bool valid = n < N_NODES;
    float acc[32];
    #pragma unroll
    for (int k = 0; k < 32; k++) acc[k] = 0.f;
    if (valid){
        int beg = begs[d], end = beg + cnts[d];
        for (int i = beg + sub; i < end; i += 8){
            int src = sorted[i];
            acc_row((const uint4*)(z + (size_t)src*ZSTRIDE), acc);
        }
        if (sub == 7) acc_row((const uint4*)(z + (size_t)n*ZSTRIDE), acc);  // self loop
    }
    #pragma unroll
    for (int k = 0; k < 32; k++){
        acc[k] += dpp_mov<DPP_XOR1>(acc[k]);   // xor 1
        acc[k] += dpp_mov<DPP_XOR2>(acc[k]);   // xor 2
        acc[k] += __shfl_xor(acc[k], 4);       // xor 4
    }
    if (sub == 0){
        float dv = valid ? dinv[n] : 0.f;
        #pragma unroll
        for (int k = 0; k < 28; k++)
            srow[d*28 + k] = fmaxf(acc[k]*dv, 0.f);   // zeros for invalid rows
    }
    __syncthreads();

    // partial Gram: 2x2 register tiling, 196 threads, replica b&15
    if (t < 196){
        float* Gr = G + (size_t)(b & (GREP-1)) * 784;
        int ti = t / 14, tj = t % 14;
        int i0 = 2*ti, j0 = 2*tj;
        float c00 = 0.f, c01 = 0.f, c10 = 0.f, c11 = 0.f;
        for (int nn = 0; nn < 64; nn++){
            const float* r = srow + nn*28;
            float a0 = r[i0], a1 = r[i0+1], b0 = r[j0], b1 = r[j0+1];
            c00 += a0*b0; c01 += a0*b1; c10 += a1*b0; c11 += a1*b1;
        }
        atomicAdd(&Gr[(i0  )*28 + j0  ], c00);
        atomicAdd(&Gr[(i0  )*28 + j0+1], c01);
        atomicAdd(&Gr[(i0+1)*28 + j0  ], c10);
        atomicAdd(&Gr[(i0+1)*28 + j0+1], c11);
    }
}

// ---------- fused MLP (reduces the 16 G replicas in a prologue) ----------
__global__ __launch_bounds__(256) void k_mlp(const float* __restrict__ G,
        const float* __restrict__ W1, const float* __restrict__ b1,
        const float* __restrict__ W2, const float* __restrict__ b2,
        float* __restrict__ outp){
    __shared__ float Gs[784];
    __shared__ float part[256];
    __shared__ float h[128];
    int t = threadIdx.x;
    for (int i = t; i < 784; i += 256){
        float s = 0.f;
        #pragma unroll
        for (int r = 0; r < GREP; r++) s += G[r*784 + i];
        Gs[i] = s;
    }
    __syncthreads();
    int j = t & 127, halfsel = t >> 7;
    const float* w = W1 + (size_t)j*784 + halfsel*392;
    const float* g = Gs + halfsel*392;
    float s = 0.f;
    for (int i = 0; i < 392; i++) s += g[i] * w[i];
    part[t] = s;
    __syncthreads();
    if (t < 128) h[t] = fmaxf(part[t] + part[t+128] + b1[t], 0.f) * W2[t];
    __syncthreads();
    for (int ofs = 64; ofs > 0; ofs >>= 1){
        if (t < ofs) h[t] += h[t + ofs];
        __syncthreads();
    }
    if (t == 0) outp[0] = 1.f / (1.f + expf(-(h[0] + b2[0])));
}

extern "C" void kernel_launch(void* const* d_in, const int* in_sizes, int n_in,
                              void* d_out, int out_size, void* d_ws, size_t ws_size,
                              hipStream_t stream){
    const float* x  = (const float*)d_in[0];
    const void*  ei = d_in[1];
    const float* qw = (const float*)d_in[2];
    const float* W1 = (const float*)d_in[3];
    const float* b1 = (const float*)d_in[4];
    const float* W2 = (const float*)d_in[5];
    const float* b2 = (const float*)d_in[6];
    float* outp = (float*)d_out;

    char* base = (char*)d_ws;
    __half*   z     = (__half*)base;   base += (size_t)N_NODES*ZSTRIDE*2;   // 3.2 MB
    unsigned* pairs = (unsigned*)base; base += (size_t)NB_BUCKETS*CAP*4;    // 9.6 MB
    float*    dinv  = (float*)base;    base += (size_t)N_NODES*4;
    float4*   cmat  = (float4*)base;   base += 448;
    float*    G     = (float*)base;    base += GREP*784*4;                  // 50 KB
    int*      bucketFill = (int*)base; base += 4096;
    int*      flag  = (int*)base;      base += 16;

    k_init<<<1, 256, 0, stream>>>(qw, ei, cmat, flag, bucketFill, G);
    k_partfeat<<<NCHUNK + FEAT_BLOCKS, 1024, 0, stream>>>(x, ei, flag, bucketFill, pairs, cmat, z);
    k_degscale<<<NB_BUCKETS, 256, 0, stream>>>(pairs, bucketFill, dinv, z);
    k_bucket<<<NB_BUCKETS, 512, 0, stream>>>(pairs, bucketFill, z, dinv, G);
    k_mlp<<<1, 256, 0, stream>>>(G, W1, b1, W2, b2, outp);
}